// Round 4
// baseline (235.864 us; speedup 1.0000x reference)
//
#include <hip/hip_runtime.h>

// NMS3D (4,4,32,256,256) fp32, strict 26-neighbor max.
// R3: separable max (vmax-of-8-rows then horizontal max3) + fully unrolled
// 8-iteration h-chunk (static register renaming, no window-shift movs) +
// 3-iteration-deep load pipeline. One wave64 = one W row (64 lanes x float4);
// w-edge neighbors via __shfl; nontemporal stores keep input resident in L3.

typedef float v4f __attribute__((ext_vector_type(4)));

constexpr int W  = 256;
constexpr int H  = 256;
constexpr int D  = 32;
constexpr int SH = W;
constexpr int SD = W * H;
constexpr int HC = 8;                 // output rows per wave
constexpr int HCHUNKS = H / HC;       // 32
constexpr int BC = 16;                // B*CH

__device__ __forceinline__ v4f vmax4(v4f a, v4f b) {
    return (v4f){fmaxf(a.x, b.x), fmaxf(a.y, b.y), fmaxf(a.z, b.z), fmaxf(a.w, b.w)};
}

__global__ __launch_bounds__(256) void nms3d_kernel(const float* __restrict__ x,
                                                    float* __restrict__ out) {
    const int wid  = (blockIdx.x << 2) | (threadIdx.x >> 6);
    const int lane = threadIdx.x & 63;
    const int hc   = wid & (HCHUNKS - 1);
    const int d    = (wid >> 5) & (D - 1);
    const int bc   = wid >> 10;
    const int col  = bc * (D * SD) + d * SD + (lane << 2);
    const int h0   = hc * HC;

    const v4f zero = (v4f){0.f, 0.f, 0.f, 0.f};

    if (d == 0 || d == D - 1) {
        #pragma unroll
        for (int i = 0; i < HC; ++i)
            __builtin_nontemporal_store(zero, (v4f*)(out + col + (h0 + i) * SH));
        return;
    }

    const float* xm = x + col - SD;
    const float* x0 = x + col;
    const float* xp = x + col + SD;

    // Slot s corresponds to absolute row h0-1+s, s = 0..9 (clamped at volume edge;
    // clamped rows only feed outputs that are zero-forced by the h-valid predicate).
    v4f raw[10][3];     // raw row triples (dz = -1, 0, +1)
    v4f pm3[10];        // max over all 3 dz rows
    v4f pm2[10];        // max over dz = +-1 rows (center excluded)
    v4f cen[10];        // dz = 0 row

    #define LOADT(s) { int hh = h0 - 1 + (s); hh = hh < 0 ? 0 : (hh > H-1 ? H-1 : hh); \
        raw[s][0] = *(const v4f*)(xm + hh * SH); \
        raw[s][1] = *(const v4f*)(x0 + hh * SH); \
        raw[s][2] = *(const v4f*)(xp + hh * SH); }
    #define REDUCET(s) { pm2[s] = vmax4(raw[s][0], raw[s][2]); \
        pm3[s] = vmax4(pm2[s], raw[s][1]); cen[s] = raw[s][1]; }

    LOADT(0) LOADT(1) LOADT(2) LOADT(3) LOADT(4)
    REDUCET(0) REDUCET(1) REDUCET(2)

    #pragma unroll
    for (int i = 0; i < HC; ++i) {
        if (i + 5 <= 9) LOADT(i + 5)        // in flight for ~3 iterations
        REDUCET(i + 3)

        const int h = h0 + i;
        // vmax over the 8 non-center rows
        v4f v8 = vmax4(vmax4(pm3[i], pm2[i + 1]), pm3[i + 2]);
        float l8 = __shfl_up(v8.w, 1);      // v8 at w0-1 (lane0 garbage, masked)
        float r8 = __shfl_down(v8.x, 1);    // v8 at w0+4 (lane63 garbage, masked)
        const v4f c = cen[i + 1];
        float lc = __shfl_up(c.w, 1);
        float rc = __shfl_down(c.x, 1);

        // hmax3 of v8 + hmax2 of center row
        float n0 = fmaxf(fmaxf(l8,   v8.x), v8.y);
        float n1 = fmaxf(fmaxf(v8.x, v8.y), v8.z);
        float n2 = fmaxf(fmaxf(v8.y, v8.z), v8.w);
        float n3 = fmaxf(fmaxf(v8.z, v8.w), r8);
        n0 = fmaxf(n0, fmaxf(lc,  c.y));
        n1 = fmaxf(n1, fmaxf(c.x, c.z));
        n2 = fmaxf(n2, fmaxf(c.y, c.w));
        n3 = fmaxf(n3, fmaxf(c.z, rc));

        const bool hv = (h > 0) && (h < H - 1);   // wave-uniform
        v4f o;
        o.x = (hv && lane > 0  && c.x > n0) ? c.x : 0.f;
        o.y = (hv && c.y > n1) ? c.y : 0.f;
        o.z = (hv && c.z > n2) ? c.z : 0.f;
        o.w = (hv && lane < 63 && c.w > n3) ? c.w : 0.f;
        __builtin_nontemporal_store(o, (v4f*)(out + col + h * SH));
    }
    #undef LOADT
    #undef REDUCET
}

extern "C" void kernel_launch(void* const* d_in, const int* in_sizes, int n_in,
                              void* d_out, int out_size, void* d_ws, size_t ws_size,
                              hipStream_t stream) {
    const float* x = (const float*)d_in[0];
    float* out = (float*)d_out;
    // waves = BC * D * HCHUNKS = 16*32*32 = 16384; 4 waves/block -> 4096 blocks
    const int grid = (BC * D * HCHUNKS) / 4;
    nms3d_kernel<<<grid, 256, 0, stream>>>(x, out);
}

// Round 5
// 232.179 us; speedup vs baseline: 1.0159x; 1.0159x over previous
//
#include <hip/hip_runtime.h>

// NMS3D (4,4,32,256,256) fp32, strict 26-neighbor max.
// R4: d-grouped blocks + batched loads.
//   - Block = 4 waves covering d0..d0+3 at the same (bc, h-chunk). The 6
//     dz-planes a block touches are shared through same-CU L1 / same-XCD L2,
//     cutting LLC-fabric read traffic from ~3.75x to ~1.9x of the input
//     (R3 post-mortem: 3 d-neighbor readers of each row landed on 3 XCDs ->
//     ~580 MB through the fabric = the ~7 TB/s wall at 82 us).
//   - All 30 row loads issued up-front per wave (no intervening compute, so
//     the compiler cannot sink them), then separable-max reduce + 8 outputs.
// One wave64 = one W row (64 lanes x float4); w-edges via __shfl;
// nontemporal stores keep input resident in L3.

typedef float v4f __attribute__((ext_vector_type(4)));

constexpr int W  = 256;
constexpr int H  = 256;
constexpr int D  = 32;
constexpr int SH = W;
constexpr int SD = W * H;
constexpr int HC = 8;                 // output rows per wave
constexpr int HCHUNKS = H / HC;       // 32
constexpr int BC = 16;                // B*CH
constexpr int DCHUNKS = D / 4;        // 8 (4 d-values per block, one per wave)

__device__ __forceinline__ v4f vmax4(v4f a, v4f b) {
    return (v4f){fmaxf(a.x, b.x), fmaxf(a.y, b.y), fmaxf(a.z, b.z), fmaxf(a.w, b.w)};
}

__global__ __launch_bounds__(256) void nms3d_kernel(const float* __restrict__ x,
                                                    float* __restrict__ out) {
    const int blk    = blockIdx.x;
    const int wlocal = threadIdx.x >> 6;          // 0..3 -> d offset in chunk
    const int lane   = threadIdx.x & 63;
    const int hc     = blk & (HCHUNKS - 1);       // fastest: adjacent blocks differ in hc
    const int dchunk = (blk >> 5) & (DCHUNKS - 1);
    const int bc     = blk >> 8;
    const int d      = (dchunk << 2) | wlocal;
    const int col    = bc * (D * SD) + d * SD + (lane << 2);
    const int h0     = hc * HC;

    const v4f zero = (v4f){0.f, 0.f, 0.f, 0.f};

    if (d == 0 || d == D - 1) {
        #pragma unroll
        for (int i = 0; i < HC; ++i)
            __builtin_nontemporal_store(zero, (v4f*)(out + col + (h0 + i) * SH));
        return;
    }

    const float* xm = x + col - SD;
    const float* x0 = x + col;
    const float* xp = x + col + SD;

    // Batch-load all 30 rows (slots 0..9 = absolute rows h0-1..h0+8, clamped;
    // clamped rows only feed outputs zero-forced by the h-valid predicate).
    v4f raw[10][3];
    #pragma unroll
    for (int s = 0; s < 10; ++s) {
        int hh = h0 - 1 + s;
        hh = hh < 0 ? 0 : (hh > H - 1 ? H - 1 : hh);
        raw[s][0] = *(const v4f*)(xm + hh * SH);
        raw[s][1] = *(const v4f*)(x0 + hh * SH);
        raw[s][2] = *(const v4f*)(xp + hh * SH);
    }

    // Separable partial maxes per slot (consumed in load order -> progressive vmcnt).
    v4f pm3[10], pm2[10], cen[10];
    #pragma unroll
    for (int s = 0; s < 10; ++s) {
        pm2[s] = vmax4(raw[s][0], raw[s][2]);     // dz = +-1
        pm3[s] = vmax4(pm2[s], raw[s][1]);        // all 3 dz
        cen[s] = raw[s][1];
    }

    #pragma unroll
    for (int i = 0; i < HC; ++i) {
        const int h = h0 + i;
        v4f v8 = vmax4(vmax4(pm3[i], pm2[i + 1]), pm3[i + 2]);   // 8 non-center rows
        float l8 = __shfl_up(v8.w, 1);
        float r8 = __shfl_down(v8.x, 1);
        const v4f c = cen[i + 1];
        float lc = __shfl_up(c.w, 1);
        float rc = __shfl_down(c.x, 1);

        float n0 = fmaxf(fmaxf(l8,   v8.x), v8.y);
        float n1 = fmaxf(fmaxf(v8.x, v8.y), v8.z);
        float n2 = fmaxf(fmaxf(v8.y, v8.z), v8.w);
        float n3 = fmaxf(fmaxf(v8.z, v8.w), r8);
        n0 = fmaxf(n0, fmaxf(lc,  c.y));
        n1 = fmaxf(n1, fmaxf(c.x, c.z));
        n2 = fmaxf(n2, fmaxf(c.y, c.w));
        n3 = fmaxf(n3, fmaxf(c.z, rc));

        const bool hv = (h > 0) && (h < H - 1);   // wave-uniform
        v4f o;
        o.x = (hv && lane > 0  && c.x > n0) ? c.x : 0.f;
        o.y = (hv && c.y > n1) ? c.y : 0.f;
        o.z = (hv && c.z > n2) ? c.z : 0.f;
        o.w = (hv && lane < 63 && c.w > n3) ? c.w : 0.f;
        __builtin_nontemporal_store(o, (v4f*)(out + col + h * SH));
    }
}

extern "C" void kernel_launch(void* const* d_in, const int* in_sizes, int n_in,
                              void* d_out, int out_size, void* d_ws, size_t ws_size,
                              hipStream_t stream) {
    const float* x = (const float*)d_in[0];
    float* out = (float*)d_out;
    // blocks = BC * DCHUNKS * HCHUNKS = 16*8*32 = 4096
    const int grid = BC * DCHUNKS * HCHUNKS;
    nms3d_kernel<<<grid, 256, 0, stream>>>(x, out);
}